// Round 1
// baseline (2337.815 us; speedup 1.0000x reference)
//
#include <hip/hip_runtime.h>
#include <math.h>

// Problem constants
#define ZS    128      // z_size
#define KS    256      // key_size
#define HS    512      // hidden
#define BATCH 512
#define TT    32
#define MM    33       // T+1 steps / memory slots
#define NB    2304     // 2048 gate cols (reordered j*4+gate) + 256 key_w cols
#define KPAD  784      // 769 (257 key_r + 512 h) padded to multiple of 16
#define LDA   784
#define KC    16

static __device__ __forceinline__ float sigf(float x) { return 1.f / (1.f + expf(-x)); }

// ---------------------------------------------------------------------------
// Weight prep: Wt[k][n] (784 x 2304) fused+reordered [W_ih | W_hh | W_key^T],
// biasN[n] fused b_ih+b_hh (reordered) then b_key.
// ---------------------------------------------------------------------------
__global__ void prep_w(const float* __restrict__ W_ih, const float* __restrict__ W_hh,
                       const float* __restrict__ W_key, const float* __restrict__ b_ih,
                       const float* __restrict__ b_hh, const float* __restrict__ b_key,
                       float* __restrict__ Wt, float* __restrict__ biasN)
{
    int idx = blockIdx.x * 256 + threadIdx.x;
    if (idx >= KPAD * NB) return;
    int k = idx / NB, n = idx - k * NB;
    float v = 0.f;
    if (n < 2048) {
        int j = n >> 2, gi = n & 3, r = gi * 512 + j;   // original row in W_ih/W_hh
        if (k < 257) v = W_ih[r * 257 + k];
        else if (k < 769) v = W_hh[r * 512 + (k - 257)];
    } else {
        if (k >= 257 && k < 769) v = W_key[(n - 2048) * 512 + (k - 257)];
    }
    Wt[idx] = v;
    if (idx < NB) {
        float bv;
        if (idx < 2048) { int j = idx >> 2, gi = idx & 3, r = gi * 512 + j; bv = b_ih[r] + b_hh[r]; }
        else bv = b_key[idx - 2048];
        biasN[idx] = bv;
    }
}

// ---------------------------------------------------------------------------
// Tiled fp32 GEMM, 32(M) x 64(N) tiles, 256 threads, micro 2x4.
// MODE 0: encoder  (C written to z_pad with [b][t][z] layout, m = b*32+t)
// MODE 1: gates    (cols <2048: fused LSTM cell -> h,c; cols >=2048: key_w -> Mk)
// ---------------------------------------------------------------------------
template<int MODE>
__global__ __launch_bounds__(256)
void gemm_k(const float* __restrict__ A, int lda,
            const float* __restrict__ B, int ldb,
            int K,
            float* __restrict__ out,            // MODE0: z_pad ; MODE1: inpN base
            const float* __restrict__ biasN,
            float* __restrict__ c_state,
            float* __restrict__ Mk,
            int step)
{
    __shared__ float As[KC][36];
    __shared__ float Bs[KC][68];
    const int tid = threadIdx.x;
    const int tx = tid & 15, ty = tid >> 4;
    const int row0 = blockIdx.y * 32, col0 = blockIdx.x * 64;

    const int am = tid >> 3;         // 0..31  (A tile row)
    const int ak = (tid & 7) * 2;    // 0..14  (A tile k, float2)
    const int bk = tid >> 4;         // 0..15  (B tile k)
    const int bn = (tid & 15) * 4;   // 0..60  (B tile n, float4)

    const float* Ap = A + (size_t)(row0 + am) * lda + ak;
    const float* Bp = B + (size_t)bk * ldb + col0 + bn;

    float acc[2][4] = {};

    for (int kc = 0; kc < K; kc += KC) {
        const float2 av = *(const float2*)(Ap + kc);
        const float4 bv = *(const float4*)(Bp + (size_t)kc * ldb);
        __syncthreads();
        As[ak + 0][am] = av.x;
        As[ak + 1][am] = av.y;
        *(float4*)&Bs[bk][bn] = bv;
        __syncthreads();
#pragma unroll
        for (int kk = 0; kk < KC; kk++) {
            const float2 a = *(const float2*)&As[kk][ty * 2];
            const float4 b = *(const float4*)&Bs[kk][tx * 4];
            acc[0][0] += a.x * b.x; acc[0][1] += a.x * b.y; acc[0][2] += a.x * b.z; acc[0][3] += a.x * b.w;
            acc[1][0] += a.y * b.x; acc[1][1] += a.y * b.y; acc[1][2] += a.y * b.z; acc[1][3] += a.y * b.w;
        }
    }

    if (MODE == 0) {
#pragma unroll
        for (int i = 0; i < 2; i++) {
            int m = row0 + ty * 2 + i;          // bt index
            int n0 = col0 + tx * 4;
            float4 v = make_float4(acc[i][0], acc[i][1], acc[i][2], acc[i][3]);
            *(float4*)&out[(size_t)(m >> 5) * (MM * ZS) + (m & 31) * ZS + n0] = v;
        }
    } else {
#pragma unroll
        for (int i = 0; i < 2; i++) {
            int b  = row0 + ty * 2 + i;         // batch row
            int n0 = col0 + tx * 4;
            float p0 = acc[i][0] + biasN[n0 + 0];
            float p1 = acc[i][1] + biasN[n0 + 1];
            float p2 = acc[i][2] + biasN[n0 + 2];
            float p3 = acc[i][3] + biasN[n0 + 3];
            if (n0 < 2048) {
                int j = n0 >> 2;                // hidden unit; p0..p3 = i,f,g,o preacts
                float co = c_state[b * HS + j];
                float ig = sigf(p0), fg = sigf(p1), gg = tanhf(p2), og = sigf(p3);
                float cn = fg * co + ig * gg;
                float hn = og * tanhf(cn);
                c_state[b * HS + j] = cn;
                out[(size_t)b * LDA + 257 + j] = hn;       // h into next-step input buffer
            } else if (step >= 1) {
                int m2 = n0 - 2048;             // key_w(step-1) dims
                float4 kw = make_float4(fmaxf(p0, 0.f), fmaxf(p1, 0.f),
                                        fmaxf(p2, 0.f), fmaxf(p3, 0.f));
                *(float4*)&Mk[((size_t)(step - 1) * BATCH + b) * KS + m2] = kw;
            }
        }
    }
}

// ---------------------------------------------------------------------------
// Context norm over T (axis=1), writes zero row t=32.
// ---------------------------------------------------------------------------
__global__ void norm_k(float* __restrict__ z_pad, const float* __restrict__ gamma,
                       const float* __restrict__ beta)
{
    int b = blockIdx.x, zc = threadIdx.x;     // 128 threads
    float* zb = z_pad + (size_t)b * (MM * ZS);
    float s = 0.f, s2 = 0.f;
    for (int t = 0; t < TT; t++) { float v = zb[t * ZS + zc]; s += v; s2 += v * v; }
    float mu = s * (1.f / 32.f);
    float var = s2 * (1.f / 32.f) - mu * mu;
    float rstd = 1.f / sqrtf(var + 1e-8f);
    float ga = gamma[zc], be = beta[zc];
    for (int t = 0; t < TT; t++) {
        float v = zb[t * ZS + zc];
        zb[t * ZS + zc] = (v - mu) * rstd * ga + be;
    }
    zb[TT * ZS + zc] = 0.f;                   // z_pad final zero row
}

// ---------------------------------------------------------------------------
// Precompute attention weights: w_att[b][t][m] = softmax_m<t(z_t . z_m),
// wc[b][t] = sum_m w * sigmoid(score*cg+cb). One block per b; 4 waves split t.
// ---------------------------------------------------------------------------
__global__ __launch_bounds__(256)
void scores_k(const float* __restrict__ z_pad, const float* __restrict__ cg_p,
              const float* __restrict__ cb_p, float* __restrict__ watt,
              float* __restrict__ wc)
{
    __shared__ float zs[MM * 129];            // +1 pad per row: conflict-free
    int b = blockIdx.x, tid = threadIdx.x;
    const float* zb = z_pad + (size_t)b * (MM * ZS);
    for (int i = tid; i < MM * ZS; i += 256) {
        int m = i >> 7, k = i & 127;
        zs[m * 129 + k] = zb[i];
    }
    __syncthreads();
    float cg = cg_p[0], cb = cb_p[0];
    int wid = tid >> 6, lane = tid & 63;
    for (int t = 1 + wid; t <= 32; t += 4) {
        int m = lane;
        float s = -3.0e38f;
        if (m < t) {
            const float* zt = &zs[t * 129];
            const float* zm = &zs[m * 129];
            float acc = 0.f;
#pragma unroll 8
            for (int k = 0; k < ZS; k++) acc += zt[k] * zm[k];
            s = acc;
        }
        float mx = s;
        for (int off = 1; off < 64; off <<= 1) mx = fmaxf(mx, __shfl_xor(mx, off));
        float e = (m < t) ? expf(s - mx) : 0.f;
        float sum = e;
        for (int off = 1; off < 64; off <<= 1) sum += __shfl_xor(sum, off);
        float w = e / sum;
        if (m < t) watt[(b * MM + t) * MM + m] = w;
        float p = (m < t) ? w * sigf(s * cg + cb) : 0.f;
        for (int off = 1; off < 64; off <<= 1) p += __shfl_xor(p, off);
        if (lane == 0) wc[b * MM + t] = p;
    }
}

// ---------------------------------------------------------------------------
// Post-step: g(t) = sigmoid(h.W_g + b_g); key_r(t+1) = g * [sum_{m<t} w*Mk ; wc].
// One block per batch row. Reads h from (and writes key_r into) the same
// ping-pong buffer (disjoint columns).
// ---------------------------------------------------------------------------
__global__ __launch_bounds__(256)
void post_k(float* __restrict__ inpN, const float* __restrict__ W_g,
            const float* __restrict__ b_g, const float* __restrict__ watt,
            const float* __restrict__ wc, const float* __restrict__ Mk, int t)
{
    __shared__ float red[256];
    __shared__ float wts[32];
    __shared__ float gsh;
    int b = blockIdx.x, tid = threadIdx.x;
    float* row = inpN + (size_t)b * LDA;
    float h1 = row[257 + tid], h2 = row[257 + 256 + tid];
    red[tid] = h1 * W_g[tid] + h2 * W_g[tid + 256];
    if (tid < t) wts[tid] = watt[(b * MM + t) * MM + tid];
    __syncthreads();
    for (int s = 128; s > 0; s >>= 1) {
        if (tid < s) red[tid] += red[tid + s];
        __syncthreads();
    }
    if (tid == 0) gsh = sigf(red[0] + b_g[0]);
    __syncthreads();
    float g = gsh;
    float acc = 0.f;
    for (int m = 0; m < t; m++)
        acc += wts[m] * Mk[((size_t)m * BATCH + b) * KS + tid];
    row[tid] = g * acc;                       // key_r dims 0..255
    if (tid == 0) row[256] = g * wc[b * MM + t];  // confidence dim
}

// ---------------------------------------------------------------------------
// Final y = h(32) @ W_y.T + b_y, plus argmax (first-max-wins, as float).
// ---------------------------------------------------------------------------
__global__ void y_k(const float* __restrict__ inpN, const float* __restrict__ W_y,
                    const float* __restrict__ b_y, float* __restrict__ out)
{
    int b = blockIdx.x, lane = threadIdx.x;   // 64 threads
    const float* h = inpN + (size_t)b * LDA + 257;
    float a0 = 0, a1 = 0, a2 = 0, a3 = 0;
    for (int r = 0; r < 8; r++) {
        int k = lane + r * 64;
        float hv = h[k];
        a0 += hv * W_y[k];
        a1 += hv * W_y[512 + k];
        a2 += hv * W_y[1024 + k];
        a3 += hv * W_y[1536 + k];
    }
    for (int off = 32; off > 0; off >>= 1) {
        a0 += __shfl_xor(a0, off);
        a1 += __shfl_xor(a1, off);
        a2 += __shfl_xor(a2, off);
        a3 += __shfl_xor(a3, off);
    }
    if (lane == 0) {
        float y0 = a0 + b_y[0], y1 = a1 + b_y[1], y2 = a2 + b_y[2], y3 = a3 + b_y[3];
        out[b * 4 + 0] = y0; out[b * 4 + 1] = y1; out[b * 4 + 2] = y2; out[b * 4 + 3] = y3;
        int best = 0; float bv = y0;
        if (y1 > bv) { bv = y1; best = 1; }
        if (y2 > bv) { bv = y2; best = 2; }
        if (y3 > bv) { bv = y3; best = 3; }
        out[2048 + b] = (float)best;
    }
}

// ---------------------------------------------------------------------------
extern "C" void kernel_launch(void* const* d_in, const int* in_sizes, int n_in,
                              void* d_out, int out_size, void* d_ws, size_t ws_size,
                              hipStream_t stream)
{
    const float* x_seq = (const float*)d_in[0];
    const float* W_enc = (const float*)d_in[1];
    const float* gamma = (const float*)d_in[2];
    const float* beta  = (const float*)d_in[3];
    const float* W_ih  = (const float*)d_in[4];
    const float* W_hh  = (const float*)d_in[5];
    const float* b_ih  = (const float*)d_in[6];
    const float* b_hh  = (const float*)d_in[7];
    const float* W_key = (const float*)d_in[8];
    const float* b_key = (const float*)d_in[9];
    const float* W_g   = (const float*)d_in[10];
    const float* b_g   = (const float*)d_in[11];
    const float* cgain = (const float*)d_in[12];
    const float* cbias = (const float*)d_in[13];
    const float* W_y   = (const float*)d_in[14];
    const float* b_y   = (const float*)d_in[15];

    float* ws    = (float*)d_ws;
    float* z_pad = ws;                        // 512*33*128 = 2,162,688
    float* Wt    = z_pad + 2162688;           // 784*2304   = 1,806,336
    float* biasN = Wt + 1806336;              // 2,304
    float* watt  = biasN + 2304;              // 512*33*33  = 557,568
    float* wcv   = watt + 557568;             // 512*33     = 16,896
    float* Mk    = wcv + 16896;               // 32*512*256 = 4,194,304
    float* inp0  = Mk + 4194304;              // 512*784    = 401,408
    float* inp1  = inp0 + 401408;             // 401,408
    float* cst   = inp1 + 401408;             // 512*512    = 262,144

    // zero h/key_r ping-pong buffers (incl. K-pad columns) + c state
    hipMemsetAsync(inp0, 0, (size_t)(401408 * 2 + 262144) * sizeof(float), stream);

    prep_w<<<7056, 256, 0, stream>>>(W_ih, W_hh, W_key, b_ih, b_hh, b_key, Wt, biasN);

    // encoder: [16384 x 1024] @ [1024 x 128] -> z_pad (pre-norm)
    gemm_k<0><<<dim3(2, 512), 256, 0, stream>>>(x_seq, 1024, W_enc, 128, 1024,
                                                z_pad, nullptr, nullptr, nullptr, 0);
    norm_k<<<512, 128, 0, stream>>>(z_pad, gamma, beta);
    scores_k<<<512, 256, 0, stream>>>(z_pad, cgain, cbias, watt, wcv);

    for (int t = 0; t <= 32; t++) {
        float* inC = (t & 1) ? inp1 : inp0;   // holds key_r(t), h(t-1)
        float* inN = (t & 1) ? inp0 : inp1;   // receives h(t), then key_r(t+1)
        gemm_k<1><<<dim3(36, 16), 256, 0, stream>>>(inC, LDA, Wt, NB, KPAD,
                                                    inN, biasN, cst, Mk, t);
        if (t >= 1 && t <= 31)
            post_k<<<512, 256, 0, stream>>>(inN, W_g, b_g, watt, wcv, Mk, t);
    }
    y_k<<<512, 64, 0, stream>>>(inp1, W_y, b_y, (float*)d_out);
}

// Round 2
// 1144.439 us; speedup vs baseline: 2.0428x; 2.0428x over previous
//
#include <hip/hip_runtime.h>
#include <math.h>

typedef unsigned short ushort;
typedef unsigned int uint;
typedef __bf16 bf16x8 __attribute__((ext_vector_type(8)));
typedef float f32x4 __attribute__((ext_vector_type(4)));

// Problem constants
#define ZS    128
#define KS    256
#define HS    512
#define BATCH 512
#define TT    32
#define MM    33
#define NB    2304      // 2048 gate cols (n = j*4+gate) + 256 key cols
#define KPAD  800       // 0..256 key_r, 257..271 zero pad, 272..783 h, 784..799 pad
#define HOFF  272
#define LDA   800

static __device__ __forceinline__ float sigf(float x) { return 1.f / (1.f + expf(-x)); }

// ---------------------------------------------------------------------------
// Weight prep: Whi/Wlo [2304][800] bf16 (n-major, k-contig) from fused
// [W_ih | pad | W_hh] with gate-interleaved cols; Behi/Belo [128][1024] from
// W_enc transposed; biasN fused.
// ---------------------------------------------------------------------------
__global__ void prep_w(const float* __restrict__ W_ih, const float* __restrict__ W_hh,
                       const float* __restrict__ W_key, const float* __restrict__ b_ih,
                       const float* __restrict__ b_hh, const float* __restrict__ b_key,
                       const float* __restrict__ W_enc,
                       ushort* __restrict__ Whi, ushort* __restrict__ Wlo,
                       ushort* __restrict__ Behi, ushort* __restrict__ Belo,
                       float* __restrict__ biasN)
{
    int idx = blockIdx.x * 256 + threadIdx.x;
    if (idx < NB) {
        float bv;
        if (idx < 2048) { int j = idx >> 2, gi = idx & 3, r = gi * 512 + j; bv = b_ih[r] + b_hh[r]; }
        else bv = b_key[idx - 2048];
        biasN[idx] = bv;
    }
    if (idx < NB * KPAD) {
        int n = idx / KPAD, k = idx - n * KPAD;
        float v = 0.f;
        if (n < 2048) {
            int j = n >> 2, gi = n & 3, r = gi * 512 + j;
            if (k < 257) v = W_ih[r * 257 + k];
            else if (k >= HOFF && k < HOFF + 512) v = W_hh[r * 512 + (k - HOFF)];
        } else {
            if (k >= HOFF && k < HOFF + 512) v = W_key[(n - 2048) * 512 + (k - HOFF)];
        }
        uint u = __float_as_uint(v);
        Whi[idx] = (ushort)(u >> 16);
        float lo = v - __uint_as_float(u & 0xFFFF0000u);
        Wlo[idx] = (ushort)(__float_as_uint(lo) >> 16);
    } else if (idx < NB * KPAD + 128 * 1024) {
        int e = idx - NB * KPAD;
        int n = e >> 10, k = e & 1023;
        float v = W_enc[k * 128 + n];
        uint u = __float_as_uint(v);
        Behi[e] = (ushort)(u >> 16);
        float lo = v - __uint_as_float(u & 0xFFFF0000u);
        Belo[e] = (ushort)(__float_as_uint(lo) >> 16);
    }
}

// ---------------------------------------------------------------------------
// bf16x3 MFMA GEMM. Block 256 thr (4 waves, 2x2), block tile 64(M) x BN(N).
// A fp32 [m][k] split hi/lo on the fly; B pre-split bf16 [n][k].
// MODE 0: encoder epilogue -> z_pad[b][t][z].
// MODE 1: gates: cols <2048 fused LSTM cell (via per-wave LDS exchange),
//         cols >=2048 relu -> Mk[step-1].
// ---------------------------------------------------------------------------
template<int BN, int MODE>
__global__ __launch_bounds__(256)
void gemm_mfma(const float* __restrict__ A, int lda,
               const ushort* __restrict__ Bhi, const ushort* __restrict__ Blo, int ldb,
               int nslice,
               float* __restrict__ out, const float* __restrict__ biasN,
               float* __restrict__ cst, float* __restrict__ Mk, int step)
{
    constexpr int NI = BN / 32;            // N subtiles per wave
    constexpr int AHI = 0, ALO = 2560, BHI = 5120, BLO = 5120 + 40 * BN;
    __shared__ ushort lds[5120 + 80 * BN]; // stride 40 bf16 per 32-k row (pad)

    const int tid = threadIdx.x;
    const int bx = blockIdx.x, by = blockIdx.y;
    const int row0 = by * 64, n0 = bx * BN;
    const int l = tid & 63, w = tid >> 6, wm = w >> 1, wn = w & 1;
    const int lm = l & 15, kg = (l >> 4) << 3;

    f32x4 acc[2][NI];
    const f32x4 zero4 = {0.f, 0.f, 0.f, 0.f};
#pragma unroll
    for (int mi = 0; mi < 2; mi++)
#pragma unroll
        for (int ni = 0; ni < NI; ni++) acc[mi][ni] = zero4;

    for (int s = 0; s < nslice; s++) {
        const int k0 = s * 32;
        // ---- global loads into regs
        float4 av[2];
#pragma unroll
        for (int i = 0; i < 2; i++) {
            int idx = tid + 256 * i, r = idx >> 3, c = (idx & 7) << 2;
            av[i] = *(const float4*)(A + (size_t)(row0 + r) * lda + k0 + c);
        }
        uint4 bhv[BN / 64], blv[BN / 64];
#pragma unroll
        for (int i = 0; i < BN / 64; i++) {
            int idx = tid + 256 * i, r = idx >> 2, c = (idx & 3) << 3;
            bhv[i] = *(const uint4*)(Bhi + (size_t)(n0 + r) * ldb + k0 + c);
            blv[i] = *(const uint4*)(Blo + (size_t)(n0 + r) * ldb + k0 + c);
        }
        __syncthreads();
        // ---- stage A (split fp32 -> hi/lo bf16)
#pragma unroll
        for (int i = 0; i < 2; i++) {
            int idx = tid + 256 * i, r = idx >> 3, c = (idx & 7) << 2;
            uint u0 = __float_as_uint(av[i].x), u1 = __float_as_uint(av[i].y);
            uint u2 = __float_as_uint(av[i].z), u3 = __float_as_uint(av[i].w);
            uint hp0 = (u1 & 0xFFFF0000u) | (u0 >> 16);
            uint hp1 = (u3 & 0xFFFF0000u) | (u2 >> 16);
            float l0 = av[i].x - __uint_as_float(u0 & 0xFFFF0000u);
            float l1 = av[i].y - __uint_as_float(u1 & 0xFFFF0000u);
            float l2 = av[i].z - __uint_as_float(u2 & 0xFFFF0000u);
            float l3 = av[i].w - __uint_as_float(u3 & 0xFFFF0000u);
            uint lp0 = (__float_as_uint(l1) & 0xFFFF0000u) | (__float_as_uint(l0) >> 16);
            uint lp1 = (__float_as_uint(l3) & 0xFFFF0000u) | (__float_as_uint(l2) >> 16);
            *(uint2*)&lds[AHI + r * 40 + c] = make_uint2(hp0, hp1);
            *(uint2*)&lds[ALO + r * 40 + c] = make_uint2(lp0, lp1);
        }
        // ---- stage B
#pragma unroll
        for (int i = 0; i < BN / 64; i++) {
            int idx = tid + 256 * i, r = idx >> 2, c = (idx & 3) << 3;
            *(uint4*)&lds[BHI + r * 40 + c] = bhv[i];
            *(uint4*)&lds[BLO + r * 40 + c] = blv[i];
        }
        __syncthreads();
        // ---- fragments + MFMA
        bf16x8 ah[2], alv[2], bh[NI], bl[NI];
#pragma unroll
        for (int mi = 0; mi < 2; mi++) {
            int r = wm * 32 + mi * 16 + lm;
            ah[mi]  = *(const bf16x8*)&lds[AHI + r * 40 + kg];
            alv[mi] = *(const bf16x8*)&lds[ALO + r * 40 + kg];
        }
#pragma unroll
        for (int ni = 0; ni < NI; ni++) {
            int r = wn * (BN / 2) + ni * 16 + lm;
            bh[ni] = *(const bf16x8*)&lds[BHI + r * 40 + kg];
            bl[ni] = *(const bf16x8*)&lds[BLO + r * 40 + kg];
        }
#pragma unroll
        for (int mi = 0; mi < 2; mi++)
#pragma unroll
            for (int ni = 0; ni < NI; ni++) {
                acc[mi][ni] = __builtin_amdgcn_mfma_f32_16x16x32_bf16(ah[mi],  bh[ni], acc[mi][ni], 0, 0, 0);
                acc[mi][ni] = __builtin_amdgcn_mfma_f32_16x16x32_bf16(ah[mi],  bl[ni], acc[mi][ni], 0, 0, 0);
                acc[mi][ni] = __builtin_amdgcn_mfma_f32_16x16x32_bf16(alv[mi], bh[ni], acc[mi][ni], 0, 0, 0);
            }
    }

    const int crow = (l >> 4) << 2;   // C/D: row = (lane>>4)*4 + reg, col = lane&15
    if (MODE == 0) {
#pragma unroll
        for (int mi = 0; mi < 2; mi++)
#pragma unroll
            for (int ni = 0; ni < NI; ni++)
#pragma unroll
                for (int r = 0; r < 4; r++) {
                    int m = row0 + wm * 32 + mi * 16 + crow + r;
                    int z = n0 + wn * (BN / 2) + ni * 16 + lm;
                    out[(size_t)(m >> 5) * (MM * ZS) + (m & 31) * ZS + z] = acc[mi][ni][r];
                }
    } else if (bx < 32) {
        // gate cols: exchange via per-wave LDS tile so one thread owns i,f,g,o
        __syncthreads();
        float* epi = (float*)lds;
        float* ew = epi + w * 1088;          // 32 x 34 region per wave
#pragma unroll
        for (int mi = 0; mi < 2; mi++)
#pragma unroll
            for (int ni = 0; ni < NI; ni++)
#pragma unroll
                for (int r = 0; r < 4; r++) {
                    int ml = mi * 16 + crow + r, nl = ni * 16 + lm;
                    ew[ml * 34 + nl] = acc[mi][ni][r] + biasN[n0 + wn * 32 + nl];
                }
        __syncthreads();
        int bl_ = tid >> 2, ug = tid & 3;
        int b = row0 + bl_;
        int j0 = bx * 16 + ug * 4;
        float4 cold = *(float4*)&cst[(size_t)b * HS + j0];
        float cc[4] = {cold.x, cold.y, cold.z, cold.w};
        float hv[4];
#pragma unroll
        for (int i = 0; i < 4; i++) {
            int ul = ug * 4 + i;
            float p[4];
#pragma unroll
            for (int g = 0; g < 4; g++) {
                int nb = ul * 4 + g;
                p[g] = epi[((bl_ >> 5) * 2 + (nb >> 5)) * 1088 + (bl_ & 31) * 34 + (nb & 31)];
            }
            float ig = sigf(p[0]), fg = sigf(p[1]), gg = tanhf(p[2]), og = sigf(p[3]);
            float cn = fg * cc[i] + ig * gg;
            hv[i] = og * tanhf(cn);
            cc[i] = cn;
        }
        *(float4*)&cst[(size_t)b * HS + j0] = make_float4(cc[0], cc[1], cc[2], cc[3]);
        *(float4*)&out[(size_t)b * LDA + HOFF + j0] = make_float4(hv[0], hv[1], hv[2], hv[3]);
    } else if (step >= 1) {
        // key cols: relu -> Mk slot step-1
#pragma unroll
        for (int mi = 0; mi < 2; mi++)
#pragma unroll
            for (int ni = 0; ni < NI; ni++)
#pragma unroll
                for (int r = 0; r < 4; r++) {
                    int b = row0 + wm * 32 + mi * 16 + crow + r;
                    int cg = n0 + wn * 32 + ni * 16 + lm;
                    float v = fmaxf(acc[mi][ni][r] + biasN[cg], 0.f);
                    Mk[((size_t)(step - 1) * BATCH + b) * KS + (cg - 2048)] = v;
                }
    }
}

// ---------------------------------------------------------------------------
// Context norm over T, writes zero row t=32.
// ---------------------------------------------------------------------------
__global__ void norm_k(float* __restrict__ z_pad, const float* __restrict__ gamma,
                       const float* __restrict__ beta)
{
    int b = blockIdx.x, zc = threadIdx.x;
    float* zb = z_pad + (size_t)b * (MM * ZS);
    float s = 0.f, s2 = 0.f;
    for (int t = 0; t < TT; t++) { float v = zb[t * ZS + zc]; s += v; s2 += v * v; }
    float mu = s * (1.f / 32.f);
    float var = s2 * (1.f / 32.f) - mu * mu;
    float rstd = 1.f / sqrtf(var + 1e-8f);
    float ga = gamma[zc], be = beta[zc];
    for (int t = 0; t < TT; t++) {
        float v = zb[t * ZS + zc];
        zb[t * ZS + zc] = (v - mu) * rstd * ga + be;
    }
    zb[TT * ZS + zc] = 0.f;
}

// ---------------------------------------------------------------------------
// Precompute attention weights + confidence sums (z-only, loop-invariant).
// ---------------------------------------------------------------------------
__global__ __launch_bounds__(256)
void scores_k(const float* __restrict__ z_pad, const float* __restrict__ cg_p,
              const float* __restrict__ cb_p, float* __restrict__ watt,
              float* __restrict__ wc)
{
    __shared__ float zs[MM * 129];
    int b = blockIdx.x, tid = threadIdx.x;
    const float* zb = z_pad + (size_t)b * (MM * ZS);
    for (int i = tid; i < MM * ZS; i += 256) {
        int m = i >> 7, k = i & 127;
        zs[m * 129 + k] = zb[i];
    }
    __syncthreads();
    float cg = cg_p[0], cb = cb_p[0];
    int wid = tid >> 6, lane = tid & 63;
    for (int t = 1 + wid; t <= 32; t += 4) {
        int m = lane;
        float s = -3.0e38f;
        if (m < t) {
            const float* zt = &zs[t * 129];
            const float* zm = &zs[m * 129];
            float acc = 0.f;
#pragma unroll 8
            for (int k = 0; k < ZS; k++) acc += zt[k] * zm[k];
            s = acc;
        }
        float mx = s;
        for (int off = 1; off < 64; off <<= 1) mx = fmaxf(mx, __shfl_xor(mx, off));
        float e = (m < t) ? expf(s - mx) : 0.f;
        float sum = e;
        for (int off = 1; off < 64; off <<= 1) sum += __shfl_xor(sum, off);
        float w = e / sum;
        if (m < t) watt[(b * MM + t) * MM + m] = w;
        float p = (m < t) ? w * sigf(s * cg + cb) : 0.f;
        for (int off = 1; off < 64; off <<= 1) p += __shfl_xor(p, off);
        if (lane == 0) wc[b * MM + t] = p;
    }
}

// ---------------------------------------------------------------------------
// Post-step: g gate + attention read -> key_r(t+1) into same ping-pong buffer.
// ---------------------------------------------------------------------------
__global__ __launch_bounds__(256)
void post_k(float* __restrict__ inpN, const float* __restrict__ W_g,
            const float* __restrict__ b_g, const float* __restrict__ watt,
            const float* __restrict__ wc, const float* __restrict__ Mk, int t)
{
    __shared__ float red[256];
    __shared__ float wts[32];
    __shared__ float gsh;
    int b = blockIdx.x, tid = threadIdx.x;
    float* row = inpN + (size_t)b * LDA;
    float h1 = row[HOFF + tid], h2 = row[HOFF + 256 + tid];
    red[tid] = h1 * W_g[tid] + h2 * W_g[tid + 256];
    if (tid < t) wts[tid] = watt[(b * MM + t) * MM + tid];
    __syncthreads();
    for (int s = 128; s > 0; s >>= 1) {
        if (tid < s) red[tid] += red[tid + s];
        __syncthreads();
    }
    if (tid == 0) gsh = sigf(red[0] + b_g[0]);
    __syncthreads();
    float g = gsh;
    float acc = 0.f;
    for (int m = 0; m < t; m++)
        acc += wts[m] * Mk[((size_t)m * BATCH + b) * KS + tid];
    row[tid] = g * acc;
    if (tid == 0) row[256] = g * wc[b * MM + t];
}

// ---------------------------------------------------------------------------
// Final y + argmax.
// ---------------------------------------------------------------------------
__global__ void y_k(const float* __restrict__ inpN, const float* __restrict__ W_y,
                    const float* __restrict__ b_y, float* __restrict__ out)
{
    int b = blockIdx.x, lane = threadIdx.x;
    const float* h = inpN + (size_t)b * LDA + HOFF;
    float a0 = 0, a1 = 0, a2 = 0, a3 = 0;
    for (int r = 0; r < 8; r++) {
        int k = lane + r * 64;
        float hv = h[k];
        a0 += hv * W_y[k];
        a1 += hv * W_y[512 + k];
        a2 += hv * W_y[1024 + k];
        a3 += hv * W_y[1536 + k];
    }
    for (int off = 32; off > 0; off >>= 1) {
        a0 += __shfl_xor(a0, off);
        a1 += __shfl_xor(a1, off);
        a2 += __shfl_xor(a2, off);
        a3 += __shfl_xor(a3, off);
    }
    if (lane == 0) {
        float y0 = a0 + b_y[0], y1 = a1 + b_y[1], y2 = a2 + b_y[2], y3 = a3 + b_y[3];
        out[b * 4 + 0] = y0; out[b * 4 + 1] = y1; out[b * 4 + 2] = y2; out[b * 4 + 3] = y3;
        int best = 0; float bv = y0;
        if (y1 > bv) { bv = y1; best = 1; }
        if (y2 > bv) { bv = y2; best = 2; }
        if (y3 > bv) { bv = y3; best = 3; }
        out[2048 + b] = (float)best;
    }
}

// ---------------------------------------------------------------------------
extern "C" void kernel_launch(void* const* d_in, const int* in_sizes, int n_in,
                              void* d_out, int out_size, void* d_ws, size_t ws_size,
                              hipStream_t stream)
{
    const float* x_seq = (const float*)d_in[0];
    const float* W_enc = (const float*)d_in[1];
    const float* gamma = (const float*)d_in[2];
    const float* beta  = (const float*)d_in[3];
    const float* W_ih  = (const float*)d_in[4];
    const float* W_hh  = (const float*)d_in[5];
    const float* b_ih  = (const float*)d_in[6];
    const float* b_hh  = (const float*)d_in[7];
    const float* W_key = (const float*)d_in[8];
    const float* b_key = (const float*)d_in[9];
    const float* W_g   = (const float*)d_in[10];
    const float* b_g   = (const float*)d_in[11];
    const float* cgain = (const float*)d_in[12];
    const float* cbias = (const float*)d_in[13];
    const float* W_y   = (const float*)d_in[14];
    const float* b_y   = (const float*)d_in[15];

    float* ws    = (float*)d_ws;
    float* z_pad = ws;                          // 2,162,688
    float* watt  = z_pad + 2162688;             // 557,568
    float* wcv   = watt + 557568;               // 16,896
    float* Mk    = wcv + 16896;                 // 4,194,304
    float* inp0  = Mk + 4194304;                // 409,600
    float* inp1  = inp0 + 409600;               // 409,600
    float* cst   = inp1 + 409600;               // 262,144
    float* biasN = cst + 262144;                // 2,304
    ushort* Whi  = (ushort*)(biasN + 2304);     // 1,843,200 us
    ushort* Wlo  = Whi + NB * KPAD;             // 1,843,200 us
    ushort* Behi = Wlo + NB * KPAD;             // 131,072 us
    ushort* Belo = Behi + 131072;               // 131,072 us

    // zero key_r/h ping-pong buffers (incl. pad cols) + c state
    hipMemsetAsync(inp0, 0, (size_t)(409600 * 2 + 262144) * sizeof(float), stream);

    prep_w<<<(NB * KPAD + 131072 + 255) / 256, 256, 0, stream>>>(
        W_ih, W_hh, W_key, b_ih, b_hh, b_key, W_enc, Whi, Wlo, Behi, Belo, biasN);

    // encoder: [16384 x 1024] @ [1024 x 128] -> z_pad
    gemm_mfma<128, 0><<<dim3(1, 256), 256, 0, stream>>>(
        x_seq, 1024, Behi, Belo, 1024, 32, z_pad, nullptr, nullptr, nullptr, 0);
    norm_k<<<512, 128, 0, stream>>>(z_pad, gamma, beta);
    scores_k<<<512, 256, 0, stream>>>(z_pad, cgain, cbias, watt, wcv);

    for (int t = 0; t <= 32; t++) {
        float* inC = (t & 1) ? inp1 : inp0;
        float* inN = (t & 1) ? inp0 : inp1;
        gemm_mfma<64, 1><<<dim3(36, 8), 256, 0, stream>>>(
            inC, LDA, Whi, Wlo, KPAD, 25, inN, biasN, cst, Mk, t);
        if (t >= 1 && t <= 31)
            post_k<<<512, 256, 0, stream>>>(inN, W_g, b_g, watt, wcv, Mk, t);
    }
    y_k<<<512, 64, 0, stream>>>(inp1, W_y, b_y, (float*)d_out);
}

// Round 3
// 1140.118 us; speedup vs baseline: 2.0505x; 1.0038x over previous
//
#include <hip/hip_runtime.h>
#include <math.h>

typedef unsigned short ushort;
typedef unsigned int uint;
typedef __bf16 bf16x8 __attribute__((ext_vector_type(8)));
typedef float f32x4 __attribute__((ext_vector_type(4)));

// Problem constants
#define ZS    128
#define KS    256
#define HS    512
#define BATCH 512
#define TT    32
#define MM    33
#define NB    2304      // 2048 gate cols (n = j*4+gate) + 256 key cols
#define KPAD  800       // 0..256 key_r, 257..271 zero pad, 272..783 h, 784..799 pad
#define HOFF  272
#define LDA   800

static __device__ __forceinline__ float sigf(float x) { return 1.f / (1.f + expf(-x)); }

// ---------------------------------------------------------------------------
// Weight prep: Whi/Wlo [2304][800] bf16 (n-major, k-contig) from fused
// [W_ih | pad | W_hh] with gate-interleaved cols; Behi/Belo [128][1024] from
// W_enc transposed; biasN fused.
// ---------------------------------------------------------------------------
__global__ void prep_w(const float* __restrict__ W_ih, const float* __restrict__ W_hh,
                       const float* __restrict__ W_key, const float* __restrict__ b_ih,
                       const float* __restrict__ b_hh, const float* __restrict__ b_key,
                       const float* __restrict__ W_enc,
                       ushort* __restrict__ Whi, ushort* __restrict__ Wlo,
                       ushort* __restrict__ Behi, ushort* __restrict__ Belo,
                       float* __restrict__ biasN)
{
    int idx = blockIdx.x * 256 + threadIdx.x;
    if (idx < NB) {
        float bv;
        if (idx < 2048) { int j = idx >> 2, gi = idx & 3, r = gi * 512 + j; bv = b_ih[r] + b_hh[r]; }
        else bv = b_key[idx - 2048];
        biasN[idx] = bv;
    }
    if (idx < NB * KPAD) {
        int n = idx / KPAD, k = idx - n * KPAD;
        float v = 0.f;
        if (n < 2048) {
            int j = n >> 2, gi = n & 3, r = gi * 512 + j;
            if (k < 257) v = W_ih[r * 257 + k];
            else if (k >= HOFF && k < HOFF + 512) v = W_hh[r * 512 + (k - HOFF)];
        } else {
            if (k >= HOFF && k < HOFF + 512) v = W_key[(n - 2048) * 512 + (k - HOFF)];
        }
        uint u = __float_as_uint(v);
        Whi[idx] = (ushort)(u >> 16);
        float lo = v - __uint_as_float(u & 0xFFFF0000u);
        Wlo[idx] = (ushort)(__float_as_uint(lo) >> 16);
    } else if (idx < NB * KPAD + 128 * 1024) {
        int e = idx - NB * KPAD;
        int n = e >> 10, k = e & 1023;
        float v = W_enc[k * 128 + n];
        uint u = __float_as_uint(v);
        Behi[e] = (ushort)(u >> 16);
        float lo = v - __uint_as_float(u & 0xFFFF0000u);
        Belo[e] = (ushort)(__float_as_uint(lo) >> 16);
    }
}

// ---------------------------------------------------------------------------
// bf16x3 MFMA GEMM, double-buffered K-loop (1 barrier/slice).
// Block 256 thr (4 waves, 2x2), block tile 64(M) x BN(N).
// A fp32 [m][k] split hi/lo on the fly; B pre-split bf16 [n][k].
// MODE 0: encoder epilogue -> z_pad[b][t][z].
// MODE 1: gates: cols <2048 fused LSTM cell (via per-wave LDS exchange),
//         cols >=2048 relu -> Mk[step-1].
// ---------------------------------------------------------------------------
template<int BN, int MODE>
__global__ __launch_bounds__(256)
void gemm_mfma(const float* __restrict__ A, int lda,
               const ushort* __restrict__ Bhi, const ushort* __restrict__ Blo, int ldb,
               int nslice,
               float* __restrict__ out, const float* __restrict__ biasN,
               float* __restrict__ cst, float* __restrict__ Mk, int step)
{
    constexpr int NI = BN / 32;            // N subtiles per wave
    constexpr int AHI = 0, ALO = 2560, BHI = 5120, BLO = 5120 + 40 * BN;
    constexpr int BUF = 5120 + 80 * BN;    // ushorts per stage buffer
    __shared__ ushort lds[2 * BUF];

    const int tid = threadIdx.x;
    const int bx = blockIdx.x, by = blockIdx.y;
    const int row0 = by * 64, n0 = bx * BN;
    const int l = tid & 63, w = tid >> 6, wm = w >> 1, wn = w & 1;
    const int lm = l & 15, kg = (l >> 4) << 3;

    f32x4 acc[2][NI];
    const f32x4 zero4 = {0.f, 0.f, 0.f, 0.f};
#pragma unroll
    for (int mi = 0; mi < 2; mi++)
#pragma unroll
        for (int ni = 0; ni < NI; ni++) acc[mi][ni] = zero4;

    // prefetch registers
    float4 av[2];
    uint4 bhv[BN / 64], blv[BN / 64];

    auto LOADG = [&](int s) {
        const int k0 = s * 32;
#pragma unroll
        for (int i = 0; i < 2; i++) {
            int idx = tid + 256 * i, r = idx >> 3, c = (idx & 7) << 2;
            av[i] = *(const float4*)(A + (size_t)(row0 + r) * lda + k0 + c);
        }
#pragma unroll
        for (int i = 0; i < BN / 64; i++) {
            int idx = tid + 256 * i, r = idx >> 2, c = (idx & 3) << 3;
            bhv[i] = *(const uint4*)(Bhi + (size_t)(n0 + r) * ldb + k0 + c);
            blv[i] = *(const uint4*)(Blo + (size_t)(n0 + r) * ldb + k0 + c);
        }
    };
    auto STORE = [&](int buf) {
        ushort* L = lds + buf * BUF;
#pragma unroll
        for (int i = 0; i < 2; i++) {
            int idx = tid + 256 * i, r = idx >> 3, c = (idx & 7) << 2;
            uint u0 = __float_as_uint(av[i].x), u1 = __float_as_uint(av[i].y);
            uint u2 = __float_as_uint(av[i].z), u3 = __float_as_uint(av[i].w);
            uint hp0 = (u1 & 0xFFFF0000u) | (u0 >> 16);
            uint hp1 = (u3 & 0xFFFF0000u) | (u2 >> 16);
            float l0 = av[i].x - __uint_as_float(u0 & 0xFFFF0000u);
            float l1 = av[i].y - __uint_as_float(u1 & 0xFFFF0000u);
            float l2 = av[i].z - __uint_as_float(u2 & 0xFFFF0000u);
            float l3 = av[i].w - __uint_as_float(u3 & 0xFFFF0000u);
            uint lp0 = (__float_as_uint(l1) & 0xFFFF0000u) | (__float_as_uint(l0) >> 16);
            uint lp1 = (__float_as_uint(l3) & 0xFFFF0000u) | (__float_as_uint(l2) >> 16);
            *(uint2*)&L[AHI + r * 40 + c] = make_uint2(hp0, hp1);
            *(uint2*)&L[ALO + r * 40 + c] = make_uint2(lp0, lp1);
        }
#pragma unroll
        for (int i = 0; i < BN / 64; i++) {
            int idx = tid + 256 * i, r = idx >> 2, c = (idx & 3) << 3;
            *(uint4*)&L[BHI + r * 40 + c] = bhv[i];
            *(uint4*)&L[BLO + r * 40 + c] = blv[i];
        }
    };

    // ---- software-pipelined K loop: 1 barrier per slice
    LOADG(0);
    STORE(0);
    for (int s = 0; s < nslice; s++) {
        if (s + 1 < nslice) LOADG(s + 1);   // async: in flight across barrier+MFMA
        __syncthreads();                     // buf[s&1] ready for all waves
        const ushort* L = lds + (s & 1) * BUF;
        bf16x8 ah[2], alv[2], bh[NI], bl[NI];
#pragma unroll
        for (int mi = 0; mi < 2; mi++) {
            int r = wm * 32 + mi * 16 + lm;
            ah[mi]  = *(const bf16x8*)&L[AHI + r * 40 + kg];
            alv[mi] = *(const bf16x8*)&L[ALO + r * 40 + kg];
        }
#pragma unroll
        for (int ni = 0; ni < NI; ni++) {
            int r = wn * (BN / 2) + ni * 16 + lm;
            bh[ni] = *(const bf16x8*)&L[BHI + r * 40 + kg];
            bl[ni] = *(const bf16x8*)&L[BLO + r * 40 + kg];
        }
#pragma unroll
        for (int mi = 0; mi < 2; mi++)
#pragma unroll
            for (int ni = 0; ni < NI; ni++) {
                acc[mi][ni] = __builtin_amdgcn_mfma_f32_16x16x32_bf16(ah[mi],  bh[ni], acc[mi][ni], 0, 0, 0);
                acc[mi][ni] = __builtin_amdgcn_mfma_f32_16x16x32_bf16(ah[mi],  bl[ni], acc[mi][ni], 0, 0, 0);
                acc[mi][ni] = __builtin_amdgcn_mfma_f32_16x16x32_bf16(alv[mi], bh[ni], acc[mi][ni], 0, 0, 0);
            }
        if (s + 1 < nslice) STORE((s + 1) & 1);   // vmcnt waits here, post-MFMA
    }

    const int crow = (l >> 4) << 2;   // C/D: row = (lane>>4)*4 + reg, col = lane&15
    if (MODE == 0) {
#pragma unroll
        for (int mi = 0; mi < 2; mi++)
#pragma unroll
            for (int ni = 0; ni < NI; ni++)
#pragma unroll
                for (int r = 0; r < 4; r++) {
                    int m = row0 + wm * 32 + mi * 16 + crow + r;
                    int z = n0 + wn * (BN / 2) + ni * 16 + lm;
                    out[(size_t)(m >> 5) * (MM * ZS) + (m & 31) * ZS + z] = acc[mi][ni][r];
                }
    } else if (bx < 32) {
        // gate cols: exchange via per-wave LDS tile so one thread owns i,f,g,o
        __syncthreads();
        float* epi = (float*)lds;
        float* ew = epi + w * 1088;          // 32 x 34 region per wave
#pragma unroll
        for (int mi = 0; mi < 2; mi++)
#pragma unroll
            for (int ni = 0; ni < NI; ni++)
#pragma unroll
                for (int r = 0; r < 4; r++) {
                    int ml = mi * 16 + crow + r, nl = ni * 16 + lm;
                    ew[ml * 34 + nl] = acc[mi][ni][r] + biasN[n0 + wn * 32 + nl];
                }
        __syncthreads();
        int bl_ = tid >> 2, ug = tid & 3;
        int b = row0 + bl_;
        int j0 = bx * 16 + ug * 4;
        float4 cold = *(float4*)&cst[(size_t)b * HS + j0];
        float cc[4] = {cold.x, cold.y, cold.z, cold.w};
        float hv[4];
#pragma unroll
        for (int i = 0; i < 4; i++) {
            int ul = ug * 4 + i;
            float p[4];
#pragma unroll
            for (int g = 0; g < 4; g++) {
                int nb = ul * 4 + g;
                p[g] = epi[((bl_ >> 5) * 2 + (nb >> 5)) * 1088 + (bl_ & 31) * 34 + (nb & 31)];
            }
            float ig = sigf(p[0]), fg = sigf(p[1]), gg = tanhf(p[2]), og = sigf(p[3]);
            float cn = fg * cc[i] + ig * gg;
            hv[i] = og * tanhf(cn);
            cc[i] = cn;
        }
        *(float4*)&cst[(size_t)b * HS + j0] = make_float4(cc[0], cc[1], cc[2], cc[3]);
        *(float4*)&out[(size_t)b * LDA + HOFF + j0] = make_float4(hv[0], hv[1], hv[2], hv[3]);
    } else if (step >= 1) {
        // key cols: relu -> Mk slot step-1
#pragma unroll
        for (int mi = 0; mi < 2; mi++)
#pragma unroll
            for (int ni = 0; ni < NI; ni++)
#pragma unroll
                for (int r = 0; r < 4; r++) {
                    int b = row0 + wm * 32 + mi * 16 + crow + r;
                    int cg = n0 + wn * 32 + ni * 16 + lm;
                    float v = fmaxf(acc[mi][ni][r] + biasN[cg], 0.f);
                    Mk[((size_t)(step - 1) * BATCH + b) * KS + (cg - 2048)] = v;
                }
    }
}

// ---------------------------------------------------------------------------
// Context norm over T, writes zero row t=32.
// ---------------------------------------------------------------------------
__global__ void norm_k(float* __restrict__ z_pad, const float* __restrict__ gamma,
                       const float* __restrict__ beta)
{
    int b = blockIdx.x, zc = threadIdx.x;
    float* zb = z_pad + (size_t)b * (MM * ZS);
    float s = 0.f, s2 = 0.f;
    for (int t = 0; t < TT; t++) { float v = zb[t * ZS + zc]; s += v; s2 += v * v; }
    float mu = s * (1.f / 32.f);
    float var = s2 * (1.f / 32.f) - mu * mu;
    float rstd = 1.f / sqrtf(var + 1e-8f);
    float ga = gamma[zc], be = beta[zc];
    for (int t = 0; t < TT; t++) {
        float v = zb[t * ZS + zc];
        zb[t * ZS + zc] = (v - mu) * rstd * ga + be;
    }
    zb[TT * ZS + zc] = 0.f;
}

// ---------------------------------------------------------------------------
// Precompute attention weights + confidence sums (z-only, loop-invariant).
// ---------------------------------------------------------------------------
__global__ __launch_bounds__(256)
void scores_k(const float* __restrict__ z_pad, const float* __restrict__ cg_p,
              const float* __restrict__ cb_p, float* __restrict__ watt,
              float* __restrict__ wc)
{
    __shared__ float zs[MM * 129];
    int b = blockIdx.x, tid = threadIdx.x;
    const float* zb = z_pad + (size_t)b * (MM * ZS);
    for (int i = tid; i < MM * ZS; i += 256) {
        int m = i >> 7, k = i & 127;
        zs[m * 129 + k] = zb[i];
    }
    __syncthreads();
    float cg = cg_p[0], cb = cb_p[0];
    int wid = tid >> 6, lane = tid & 63;
    for (int t = 1 + wid; t <= 32; t += 4) {
        int m = lane;
        float s = -3.0e38f;
        if (m < t) {
            const float* zt = &zs[t * 129];
            const float* zm = &zs[m * 129];
            float acc = 0.f;
#pragma unroll 8
            for (int k = 0; k < ZS; k++) acc += zt[k] * zm[k];
            s = acc;
        }
        float mx = s;
        for (int off = 1; off < 64; off <<= 1) mx = fmaxf(mx, __shfl_xor(mx, off));
        float e = (m < t) ? expf(s - mx) : 0.f;
        float sum = e;
        for (int off = 1; off < 64; off <<= 1) sum += __shfl_xor(sum, off);
        float w = e / sum;
        if (m < t) watt[(b * MM + t) * MM + m] = w;
        float p = (m < t) ? w * sigf(s * cg + cb) : 0.f;
        for (int off = 1; off < 64; off <<= 1) p += __shfl_xor(p, off);
        if (lane == 0) wc[b * MM + t] = p;
    }
}

// ---------------------------------------------------------------------------
// Post-step: g gate + attention read -> key_r(t+1) into same ping-pong buffer.
// ---------------------------------------------------------------------------
__global__ __launch_bounds__(256)
void post_k(float* __restrict__ inpN, const float* __restrict__ W_g,
            const float* __restrict__ b_g, const float* __restrict__ watt,
            const float* __restrict__ wc, const float* __restrict__ Mk, int t)
{
    __shared__ float red[256];
    __shared__ float wts[32];
    __shared__ float gsh;
    int b = blockIdx.x, tid = threadIdx.x;
    float* row = inpN + (size_t)b * LDA;
    float h1 = row[HOFF + tid], h2 = row[HOFF + 256 + tid];
    red[tid] = h1 * W_g[tid] + h2 * W_g[tid + 256];
    if (tid < t) wts[tid] = watt[(b * MM + t) * MM + tid];
    __syncthreads();
    for (int s = 128; s > 0; s >>= 1) {
        if (tid < s) red[tid] += red[tid + s];
        __syncthreads();
    }
    if (tid == 0) gsh = sigf(red[0] + b_g[0]);
    __syncthreads();
    float g = gsh;
    float acc = 0.f;
    for (int m = 0; m < t; m++)
        acc += wts[m] * Mk[((size_t)m * BATCH + b) * KS + tid];
    row[tid] = g * acc;
    if (tid == 0) row[256] = g * wc[b * MM + t];
}

// ---------------------------------------------------------------------------
// Final y + argmax.
// ---------------------------------------------------------------------------
__global__ void y_k(const float* __restrict__ inpN, const float* __restrict__ W_y,
                    const float* __restrict__ b_y, float* __restrict__ out)
{
    int b = blockIdx.x, lane = threadIdx.x;
    const float* h = inpN + (size_t)b * LDA + HOFF;
    float a0 = 0, a1 = 0, a2 = 0, a3 = 0;
    for (int r = 0; r < 8; r++) {
        int k = lane + r * 64;
        float hv = h[k];
        a0 += hv * W_y[k];
        a1 += hv * W_y[512 + k];
        a2 += hv * W_y[1024 + k];
        a3 += hv * W_y[1536 + k];
    }
    for (int off = 32; off > 0; off >>= 1) {
        a0 += __shfl_xor(a0, off);
        a1 += __shfl_xor(a1, off);
        a2 += __shfl_xor(a2, off);
        a3 += __shfl_xor(a3, off);
    }
    if (lane == 0) {
        float y0 = a0 + b_y[0], y1 = a1 + b_y[1], y2 = a2 + b_y[2], y3 = a3 + b_y[3];
        out[b * 4 + 0] = y0; out[b * 4 + 1] = y1; out[b * 4 + 2] = y2; out[b * 4 + 3] = y3;
        int best = 0; float bv = y0;
        if (y1 > bv) { bv = y1; best = 1; }
        if (y2 > bv) { bv = y2; best = 2; }
        if (y3 > bv) { bv = y3; best = 3; }
        out[2048 + b] = (float)best;
    }
}

// ---------------------------------------------------------------------------
extern "C" void kernel_launch(void* const* d_in, const int* in_sizes, int n_in,
                              void* d_out, int out_size, void* d_ws, size_t ws_size,
                              hipStream_t stream)
{
    const float* x_seq = (const float*)d_in[0];
    const float* W_enc = (const float*)d_in[1];
    const float* gamma = (const float*)d_in[2];
    const float* beta  = (const float*)d_in[3];
    const float* W_ih  = (const float*)d_in[4];
    const float* W_hh  = (const float*)d_in[5];
    const float* b_ih  = (const float*)d_in[6];
    const float* b_hh  = (const float*)d_in[7];
    const float* W_key = (const float*)d_in[8];
    const float* b_key = (const float*)d_in[9];
    const float* W_g   = (const float*)d_in[10];
    const float* b_g   = (const float*)d_in[11];
    const float* cgain = (const float*)d_in[12];
    const float* cbias = (const float*)d_in[13];
    const float* W_y   = (const float*)d_in[14];
    const float* b_y   = (const float*)d_in[15];

    float* ws    = (float*)d_ws;
    float* z_pad = ws;                          // 2,162,688
    float* watt  = z_pad + 2162688;             // 557,568
    float* wcv   = watt + 557568;               // 16,896
    float* Mk    = wcv + 16896;                 // 4,194,304
    float* inp0  = Mk + 4194304;                // 409,600
    float* inp1  = inp0 + 409600;               // 409,600
    float* cst   = inp1 + 409600;               // 262,144
    float* biasN = cst + 262144;                // 2,304
    ushort* Whi  = (ushort*)(biasN + 2304);     // 1,843,200 us
    ushort* Wlo  = Whi + NB * KPAD;             // 1,843,200 us
    ushort* Behi = Wlo + NB * KPAD;             // 131,072 us
    ushort* Belo = Behi + 131072;               // 131,072 us

    // zero key_r/h ping-pong buffers (incl. pad cols) + c state
    hipMemsetAsync(inp0, 0, (size_t)(409600 * 2 + 262144) * sizeof(float), stream);

    prep_w<<<(NB * KPAD + 131072 + 255) / 256, 256, 0, stream>>>(
        W_ih, W_hh, W_key, b_ih, b_hh, b_key, W_enc, Whi, Wlo, Behi, Belo, biasN);

    // encoder: [16384 x 1024] @ [1024 x 128] -> z_pad
    gemm_mfma<128, 0><<<dim3(1, 256), 256, 0, stream>>>(
        x_seq, 1024, Behi, Belo, 1024, 32, z_pad, nullptr, nullptr, nullptr, 0);
    norm_k<<<512, 128, 0, stream>>>(z_pad, gamma, beta);
    scores_k<<<512, 256, 0, stream>>>(z_pad, cgain, cbias, watt, wcv);

    for (int t = 0; t <= 32; t++) {
        float* inC = (t & 1) ? inp1 : inp0;
        float* inN = (t & 1) ? inp0 : inp1;
        gemm_mfma<64, 1><<<dim3(36, 8), 256, 0, stream>>>(
            inC, LDA, Whi, Wlo, KPAD, 25, inN, biasN, cst, Mk, t);
        if (t >= 1 && t <= 31)
            post_k<<<512, 256, 0, stream>>>(inN, W_g, b_g, watt, wcv, Mk, t);
    }
    y_k<<<512, 64, 0, stream>>>(inp1, W_y, b_y, (float*)d_out);
}

// Round 4
// 1014.612 us; speedup vs baseline: 2.3041x; 1.1237x over previous
//
#include <hip/hip_runtime.h>
#include <math.h>

typedef unsigned short ushort;
typedef unsigned int uint;
typedef __bf16 bf16x8 __attribute__((ext_vector_type(8)));
typedef float f32x4 __attribute__((ext_vector_type(4)));

// Problem constants
#define ZS    128
#define KS    256
#define HS    512
#define BATCH 512
#define TT    32
#define MM    33
#define NB    2304      // 2048 gate cols (n = j*4+gate) + 256 key cols
#define KPAD  800       // 0..256 key_r, 257..271 zero pad, 272..783 h, 784..799 pad
#define HOFF  272
#define LDA   800

static __device__ __forceinline__ float sigf(float x) { return 1.f / (1.f + expf(-x)); }
static __device__ __forceinline__ float bf2f(ushort u) { return __uint_as_float((uint)u << 16); }

// ---------------------------------------------------------------------------
// Weight prep: Whi/Wlo [2304][800] bf16 (n-major, k-contig); Behi/Belo
// [128][1024] from W_enc transposed; biasN fused.
// ---------------------------------------------------------------------------
__global__ void prep_w(const float* __restrict__ W_ih, const float* __restrict__ W_hh,
                       const float* __restrict__ W_key, const float* __restrict__ b_ih,
                       const float* __restrict__ b_hh, const float* __restrict__ b_key,
                       const float* __restrict__ W_enc,
                       ushort* __restrict__ Whi, ushort* __restrict__ Wlo,
                       ushort* __restrict__ Behi, ushort* __restrict__ Belo,
                       float* __restrict__ biasN)
{
    int idx = blockIdx.x * 256 + threadIdx.x;
    if (idx < NB) {
        float bv;
        if (idx < 2048) { int j = idx >> 2, gi = idx & 3, r = gi * 512 + j; bv = b_ih[r] + b_hh[r]; }
        else bv = b_key[idx - 2048];
        biasN[idx] = bv;
    }
    if (idx < NB * KPAD) {
        int n = idx / KPAD, k = idx - n * KPAD;
        float v = 0.f;
        if (n < 2048) {
            int j = n >> 2, gi = n & 3, r = gi * 512 + j;
            if (k < 257) v = W_ih[r * 257 + k];
            else if (k >= HOFF && k < HOFF + 512) v = W_hh[r * 512 + (k - HOFF)];
        } else {
            if (k >= HOFF && k < HOFF + 512) v = W_key[(n - 2048) * 512 + (k - HOFF)];
        }
        uint u = __float_as_uint(v);
        Whi[idx] = (ushort)(u >> 16);
        float lo = v - __uint_as_float(u & 0xFFFF0000u);
        Wlo[idx] = (ushort)(__float_as_uint(lo) >> 16);
    } else if (idx < NB * KPAD + 128 * 1024) {
        int e = idx - NB * KPAD;
        int n = e >> 10, k = e & 1023;
        float v = W_enc[k * 128 + n];
        uint u = __float_as_uint(v);
        Behi[e] = (ushort)(u >> 16);
        float lo = v - __uint_as_float(u & 0xFFFF0000u);
        Belo[e] = (ushort)(__float_as_uint(lo) >> 16);
    }
}

// ---------------------------------------------------------------------------
// bf16x3 MFMA GEMM, dbuf K-loop, 1 barrier/slice. Block tile BM=32 x BN.
// 4 waves in 2x2: wave = 16 rows x BN/2 cols.
// PRESPLIT: A given as bf16 hi/lo [m][k]; else A fp32 split on the fly.
// MODE 0: encoder -> z_pad[b][t][z].  MODE 1: gates+cell / key->Mk.
// ---------------------------------------------------------------------------
template<int BN, int MODE, bool PRESPLIT>
__global__ __launch_bounds__(256, 4)
void gemm_mfma(const float* __restrict__ A,
               const ushort* __restrict__ Ahi, const ushort* __restrict__ Alo, int lda,
               const ushort* __restrict__ Bhi, const ushort* __restrict__ Blo, int ldb,
               int nslice,
               float* __restrict__ out,              // MODE0: z_pad
               ushort* __restrict__ outHi, ushort* __restrict__ outLo,  // MODE1: next input
               const float* __restrict__ biasN,
               float* __restrict__ cst, float* __restrict__ Mk, int step)
{
    constexpr int NI = BN / 32;            // N subtiles per wave
    constexpr int AHI = 0, ALO = 32 * 40, BHI = 64 * 40, BLO = 64 * 40 + BN * 40;
    constexpr int BUF = 64 * 40 + 2 * BN * 40;   // ushorts per stage buffer
    __shared__ ushort lds[2 * BUF];

    const int tid = threadIdx.x;
    const int bx = blockIdx.x, by = blockIdx.y;
    const int row0 = by * 32, n0 = bx * BN;
    const int l = tid & 63, w = tid >> 6, wm = w >> 1, wn = w & 1;
    const int lm = l & 15, kg = (l >> 4) << 3;

    f32x4 acc[NI];
    const f32x4 zero4 = {0.f, 0.f, 0.f, 0.f};
#pragma unroll
    for (int ni = 0; ni < NI; ni++) acc[ni] = zero4;

    float4 avf;
    uint4 avu;
    uint4 bhv[BN / 64], blv[BN / 64];

    auto LOADG = [&](int s) {
        const int k0 = s * 32;
        if (PRESPLIT) {
            int idx = tid & 127, r = idx >> 2, c = (idx & 3) << 3;
            const ushort* src = (tid < 128) ? Ahi : Alo;
            avu = *(const uint4*)(src + (size_t)(row0 + r) * lda + k0 + c);
        } else {
            int r = tid >> 3, c = (tid & 7) << 2;
            avf = *(const float4*)(A + (size_t)(row0 + r) * lda + k0 + c);
        }
#pragma unroll
        for (int i = 0; i < BN / 64; i++) {
            int idx = tid + 256 * i, r = idx >> 2, c = (idx & 3) << 3;
            bhv[i] = *(const uint4*)(Bhi + (size_t)(n0 + r) * ldb + k0 + c);
            blv[i] = *(const uint4*)(Blo + (size_t)(n0 + r) * ldb + k0 + c);
        }
    };
    auto STORE = [&](int buf) {
        ushort* L = lds + buf * BUF;
        if (PRESPLIT) {
            int idx = tid & 127, r = idx >> 2, c = (idx & 3) << 3;
            *(uint4*)&L[(tid < 128 ? AHI : ALO) + r * 40 + c] = avu;
        } else {
            int r = tid >> 3, c = (tid & 7) << 2;
            uint u0 = __float_as_uint(avf.x), u1 = __float_as_uint(avf.y);
            uint u2 = __float_as_uint(avf.z), u3 = __float_as_uint(avf.w);
            uint hp0 = (u1 & 0xFFFF0000u) | (u0 >> 16);
            uint hp1 = (u3 & 0xFFFF0000u) | (u2 >> 16);
            float l0 = avf.x - __uint_as_float(u0 & 0xFFFF0000u);
            float l1 = avf.y - __uint_as_float(u1 & 0xFFFF0000u);
            float l2 = avf.z - __uint_as_float(u2 & 0xFFFF0000u);
            float l3 = avf.w - __uint_as_float(u3 & 0xFFFF0000u);
            uint lp0 = (__float_as_uint(l1) & 0xFFFF0000u) | (__float_as_uint(l0) >> 16);
            uint lp1 = (__float_as_uint(l3) & 0xFFFF0000u) | (__float_as_uint(l2) >> 16);
            *(uint2*)&L[AHI + r * 40 + c] = make_uint2(hp0, hp1);
            *(uint2*)&L[ALO + r * 40 + c] = make_uint2(lp0, lp1);
        }
#pragma unroll
        for (int i = 0; i < BN / 64; i++) {
            int idx = tid + 256 * i, r = idx >> 2, c = (idx & 3) << 3;
            *(uint4*)&L[BHI + r * 40 + c] = bhv[i];
            *(uint4*)&L[BLO + r * 40 + c] = blv[i];
        }
    };

    LOADG(0);
    STORE(0);
    for (int s = 0; s < nslice; s++) {
        if (s + 1 < nslice) LOADG(s + 1);
        __syncthreads();
        const ushort* L = lds + (s & 1) * BUF;
        bf16x8 ah, alv, bh[NI], bl[NI];
        {
            int r = wm * 16 + lm;
            ah  = *(const bf16x8*)&L[AHI + r * 40 + kg];
            alv = *(const bf16x8*)&L[ALO + r * 40 + kg];
        }
#pragma unroll
        for (int ni = 0; ni < NI; ni++) {
            int r = wn * (BN / 2) + ni * 16 + lm;
            bh[ni] = *(const bf16x8*)&L[BHI + r * 40 + kg];
            bl[ni] = *(const bf16x8*)&L[BLO + r * 40 + kg];
        }
#pragma unroll
        for (int ni = 0; ni < NI; ni++) {
            acc[ni] = __builtin_amdgcn_mfma_f32_16x16x32_bf16(ah,  bh[ni], acc[ni], 0, 0, 0);
            acc[ni] = __builtin_amdgcn_mfma_f32_16x16x32_bf16(ah,  bl[ni], acc[ni], 0, 0, 0);
            acc[ni] = __builtin_amdgcn_mfma_f32_16x16x32_bf16(alv, bh[ni], acc[ni], 0, 0, 0);
        }
        if (s + 1 < nslice) STORE((s + 1) & 1);
    }

    const int crow = (l >> 4) << 2;   // C/D: row = (lane>>4)*4 + reg, col = lane&15
    if (MODE == 0) {
#pragma unroll
        for (int ni = 0; ni < NI; ni++)
#pragma unroll
            for (int r = 0; r < 4; r++) {
                int m = row0 + wm * 16 + crow + r;
                int z = n0 + wn * (BN / 2) + ni * 16 + lm;
                out[(size_t)(m >> 5) * (MM * ZS) + (m & 31) * ZS + z] = acc[ni][r];
            }
    } else if (bx < 32) {
        // gate cols: per-wave LDS exchange so one thread owns i,f,g,o of a unit
        __syncthreads();
        float* epi = (float*)lds;
        float* ew = epi + w * 544;           // 16 rows x 34 stride per wave
#pragma unroll
        for (int ni = 0; ni < NI; ni++)
#pragma unroll
            for (int r = 0; r < 4; r++) {
                int ml = crow + r, nl = ni * 16 + lm;
                ew[ml * 34 + nl] = acc[ni][r] + biasN[n0 + wn * 32 + nl];
            }
        __syncthreads();
        int row = tid >> 3, jj8 = tid & 7;   // row 0..31, j-pair 0..7
        int b = row0 + row;
        int j0 = bx * 16 + jj8 * 2;
        float2 cold = *(float2*)&cst[(size_t)b * HS + j0];
        float cc[2] = {cold.x, cold.y}, hv[2];
#pragma unroll
        for (int i = 0; i < 2; i++) {
            int jj = jj8 * 2 + i;
            float p[4];
#pragma unroll
            for (int g = 0; g < 4; g++) {
                int n = jj * 4 + g;
                int wv = (row >> 4) * 2 + (n >> 5);
                p[g] = epi[wv * 544 + (row & 15) * 34 + (n & 31)];
            }
            float ig = sigf(p[0]), fg = sigf(p[1]), gg = tanhf(p[2]), og = sigf(p[3]);
            float cn = fg * cc[i] + ig * gg;
            hv[i] = og * tanhf(cn);
            cc[i] = cn;
        }
        *(float2*)&cst[(size_t)b * HS + j0] = make_float2(cc[0], cc[1]);
        // write h pre-split bf16 hi/lo into next-step input
        uint u0 = __float_as_uint(hv[0]), u1 = __float_as_uint(hv[1]);
        uint hp = (u1 & 0xFFFF0000u) | (u0 >> 16);
        float l0 = hv[0] - __uint_as_float(u0 & 0xFFFF0000u);
        float l1 = hv[1] - __uint_as_float(u1 & 0xFFFF0000u);
        uint lp = (__float_as_uint(l1) & 0xFFFF0000u) | (__float_as_uint(l0) >> 16);
        *(uint*)&outHi[(size_t)b * LDA + HOFF + j0] = hp;
        *(uint*)&outLo[(size_t)b * LDA + HOFF + j0] = lp;
    } else if (step >= 1) {
        // key cols: relu -> Mk slot step-1
#pragma unroll
        for (int ni = 0; ni < NI; ni++)
#pragma unroll
            for (int r = 0; r < 4; r++) {
                int b = row0 + wm * 16 + crow + r;
                int cg = n0 + wn * 32 + ni * 16 + lm;
                float v = fmaxf(acc[ni][r] + biasN[cg], 0.f);
                Mk[((size_t)(step - 1) * BATCH + b) * KS + (cg - 2048)] = v;
            }
    }
}

// ---------------------------------------------------------------------------
// Context norm over T, writes zero row t=32.
// ---------------------------------------------------------------------------
__global__ void norm_k(float* __restrict__ z_pad, const float* __restrict__ gamma,
                       const float* __restrict__ beta)
{
    int b = blockIdx.x, zc = threadIdx.x;
    float* zb = z_pad + (size_t)b * (MM * ZS);
    float s = 0.f, s2 = 0.f;
    for (int t = 0; t < TT; t++) { float v = zb[t * ZS + zc]; s += v; s2 += v * v; }
    float mu = s * (1.f / 32.f);
    float var = s2 * (1.f / 32.f) - mu * mu;
    float rstd = 1.f / sqrtf(var + 1e-8f);
    float ga = gamma[zc], be = beta[zc];
    for (int t = 0; t < TT; t++) {
        float v = zb[t * ZS + zc];
        zb[t * ZS + zc] = (v - mu) * rstd * ga + be;
    }
    zb[TT * ZS + zc] = 0.f;
}

// ---------------------------------------------------------------------------
// Precompute attention weights + confidence sums (z-only, loop-invariant).
// ---------------------------------------------------------------------------
__global__ __launch_bounds__(256)
void scores_k(const float* __restrict__ z_pad, const float* __restrict__ cg_p,
              const float* __restrict__ cb_p, float* __restrict__ watt,
              float* __restrict__ wc)
{
    __shared__ float zs[MM * 129];
    int b = blockIdx.x, tid = threadIdx.x;
    const float* zb = z_pad + (size_t)b * (MM * ZS);
    for (int i = tid; i < MM * ZS; i += 256) {
        int m = i >> 7, k = i & 127;
        zs[m * 129 + k] = zb[i];
    }
    __syncthreads();
    float cg = cg_p[0], cb = cb_p[0];
    int wid = tid >> 6, lane = tid & 63;
    for (int t = 1 + wid; t <= 32; t += 4) {
        int m = lane;
        float s = -3.0e38f;
        if (m < t) {
            const float* zt = &zs[t * 129];
            const float* zm = &zs[m * 129];
            float acc = 0.f;
#pragma unroll 8
            for (int k = 0; k < ZS; k++) acc += zt[k] * zm[k];
            s = acc;
        }
        float mx = s;
        for (int off = 1; off < 64; off <<= 1) mx = fmaxf(mx, __shfl_xor(mx, off));
        float e = (m < t) ? expf(s - mx) : 0.f;
        float sum = e;
        for (int off = 1; off < 64; off <<= 1) sum += __shfl_xor(sum, off);
        float w = e / sum;
        if (m < t) watt[(b * MM + t) * MM + m] = w;
        float p = (m < t) ? w * sigf(s * cg + cb) : 0.f;
        for (int off = 1; off < 64; off <<= 1) p += __shfl_xor(p, off);
        if (lane == 0) wc[b * MM + t] = p;
    }
}

// ---------------------------------------------------------------------------
// Post-step: g gate + attention read -> key_r(t+1) (bf16 hi/lo) into the
// same ping-pong buffer (disjoint cols vs h).
// ---------------------------------------------------------------------------
__global__ __launch_bounds__(256)
void post_k(ushort* __restrict__ inpHi, ushort* __restrict__ inpLo,
            const float* __restrict__ W_g, const float* __restrict__ b_g,
            const float* __restrict__ watt, const float* __restrict__ wc,
            const float* __restrict__ Mk, int t)
{
    __shared__ float red[256];
    __shared__ float wts[32];
    __shared__ float gsh;
    int b = blockIdx.x, tid = threadIdx.x;
    ushort* rHi = inpHi + (size_t)b * LDA;
    ushort* rLo = inpLo + (size_t)b * LDA;
    float h1 = bf2f(rHi[HOFF + tid]) + bf2f(rLo[HOFF + tid]);
    float h2 = bf2f(rHi[HOFF + 256 + tid]) + bf2f(rLo[HOFF + 256 + tid]);
    red[tid] = h1 * W_g[tid] + h2 * W_g[tid + 256];
    if (tid < t) wts[tid] = watt[(b * MM + t) * MM + tid];
    __syncthreads();
    for (int s = 128; s > 0; s >>= 1) {
        if (tid < s) red[tid] += red[tid + s];
        __syncthreads();
    }
    if (tid == 0) gsh = sigf(red[0] + b_g[0]);
    __syncthreads();
    float g = gsh;
    float acc = 0.f;
    for (int m = 0; m < t; m++)
        acc += wts[m] * Mk[((size_t)m * BATCH + b) * KS + tid];
    float v = g * acc;
    uint u = __float_as_uint(v);
    rHi[tid] = (ushort)(u >> 16);
    float lo = v - __uint_as_float(u & 0xFFFF0000u);
    rLo[tid] = (ushort)(__float_as_uint(lo) >> 16);
    if (tid == 0) {
        float vc = g * wc[b * MM + t];
        uint uc = __float_as_uint(vc);
        rHi[256] = (ushort)(uc >> 16);
        float lc = vc - __uint_as_float(uc & 0xFFFF0000u);
        rLo[256] = (ushort)(__float_as_uint(lc) >> 16);
    }
}

// ---------------------------------------------------------------------------
// Final y + argmax.
// ---------------------------------------------------------------------------
__global__ void y_k(const ushort* __restrict__ inpHi, const ushort* __restrict__ inpLo,
                    const float* __restrict__ W_y, const float* __restrict__ b_y,
                    float* __restrict__ out)
{
    int b = blockIdx.x, lane = threadIdx.x;
    const ushort* hHi = inpHi + (size_t)b * LDA + HOFF;
    const ushort* hLo = inpLo + (size_t)b * LDA + HOFF;
    float a0 = 0, a1 = 0, a2 = 0, a3 = 0;
    for (int r = 0; r < 8; r++) {
        int k = lane + r * 64;
        float hv = bf2f(hHi[k]) + bf2f(hLo[k]);
        a0 += hv * W_y[k];
        a1 += hv * W_y[512 + k];
        a2 += hv * W_y[1024 + k];
        a3 += hv * W_y[1536 + k];
    }
    for (int off = 32; off > 0; off >>= 1) {
        a0 += __shfl_xor(a0, off);
        a1 += __shfl_xor(a1, off);
        a2 += __shfl_xor(a2, off);
        a3 += __shfl_xor(a3, off);
    }
    if (lane == 0) {
        float y0 = a0 + b_y[0], y1 = a1 + b_y[1], y2 = a2 + b_y[2], y3 = a3 + b_y[3];
        out[b * 4 + 0] = y0; out[b * 4 + 1] = y1; out[b * 4 + 2] = y2; out[b * 4 + 3] = y3;
        int best = 0; float bv = y0;
        if (y1 > bv) { bv = y1; best = 1; }
        if (y2 > bv) { bv = y2; best = 2; }
        if (y3 > bv) { bv = y3; best = 3; }
        out[2048 + b] = (float)best;
    }
}

// ---------------------------------------------------------------------------
extern "C" void kernel_launch(void* const* d_in, const int* in_sizes, int n_in,
                              void* d_out, int out_size, void* d_ws, size_t ws_size,
                              hipStream_t stream)
{
    const float* x_seq = (const float*)d_in[0];
    const float* W_enc = (const float*)d_in[1];
    const float* gamma = (const float*)d_in[2];
    const float* beta  = (const float*)d_in[3];
    const float* W_ih  = (const float*)d_in[4];
    const float* W_hh  = (const float*)d_in[5];
    const float* b_ih  = (const float*)d_in[6];
    const float* b_hh  = (const float*)d_in[7];
    const float* W_key = (const float*)d_in[8];
    const float* b_key = (const float*)d_in[9];
    const float* W_g   = (const float*)d_in[10];
    const float* b_g   = (const float*)d_in[11];
    const float* cgain = (const float*)d_in[12];
    const float* cbias = (const float*)d_in[13];
    const float* W_y   = (const float*)d_in[14];
    const float* b_y   = (const float*)d_in[15];

    float* ws    = (float*)d_ws;
    float* z_pad = ws;                          // 2,162,688 f
    float* watt  = z_pad + 2162688;             // 557,568 f
    float* wcv   = watt + 557568;               // 16,896 f
    float* Mk    = wcv + 16896;                 // 4,194,304 f
    float* biasN = Mk + 4194304;                // 2,304 f
    float* cst   = biasN + 2304;                // 262,144 f
    ushort* inpHi0 = (ushort*)(cst + 262144);   // 409,600 us each
    ushort* inpLo0 = inpHi0 + 409600;
    ushort* inpHi1 = inpLo0 + 409600;
    ushort* inpLo1 = inpHi1 + 409600;
    ushort* Whi  = inpLo1 + 409600;             // 1,843,200 us
    ushort* Wlo  = Whi + NB * KPAD;             // 1,843,200 us
    ushort* Behi = Wlo + NB * KPAD;             // 131,072 us
    ushort* Belo = Behi + 131072;               // 131,072 us

    // zero c-state + all 4 input ping-pong buffers (contiguous region)
    hipMemsetAsync(cst, 0, 262144 * sizeof(float) + 4 * 409600 * sizeof(ushort), stream);

    prep_w<<<(NB * KPAD + 131072 + 255) / 256, 256, 0, stream>>>(
        W_ih, W_hh, W_key, b_ih, b_hh, b_key, W_enc, Whi, Wlo, Behi, Belo, biasN);

    // encoder: [16384 x 1024] @ [1024 x 128] -> z_pad
    gemm_mfma<128, 0, false><<<dim3(1, 512), 256, 0, stream>>>(
        x_seq, nullptr, nullptr, 1024, Behi, Belo, 1024, 32,
        z_pad, nullptr, nullptr, nullptr, nullptr, nullptr, 0);
    norm_k<<<512, 128, 0, stream>>>(z_pad, gamma, beta);
    scores_k<<<512, 256, 0, stream>>>(z_pad, cgain, cbias, watt, wcv);

    for (int t = 0; t <= 32; t++) {
        ushort* inHiC = (t & 1) ? inpHi1 : inpHi0;
        ushort* inLoC = (t & 1) ? inpLo1 : inpLo0;
        ushort* inHiN = (t & 1) ? inpHi0 : inpHi1;
        ushort* inLoN = (t & 1) ? inpLo0 : inpLo1;
        gemm_mfma<64, 1, true><<<dim3(36, 16), 256, 0, stream>>>(
            nullptr, inHiC, inLoC, LDA, Whi, Wlo, KPAD, 25,
            nullptr, inHiN, inLoN, biasN, cst, Mk, t);
        if (t >= 1 && t <= 31)
            post_k<<<512, 256, 0, stream>>>(inHiN, inLoN, W_g, b_g, watt, wcv, Mk, t);
    }
    y_k<<<512, 64, 0, stream>>>((0 ? inpHi0 : inpHi1), (0 ? inpLo0 : inpLo1),
                                W_y, b_y, (float*)d_out);
}